// Round 5
// baseline (2106.654 us; speedup 1.0000x reference)
//
#include <hip/hip_runtime.h>
#include <hip/hip_bf16.h>

#define CDIV(a, b) (((a) + (b) - 1) / (b))

__device__ __forceinline__ float bf2f(unsigned short u) {
  union { unsigned int i; float f; } c; c.i = ((unsigned int)u) << 16; return c.f;
}
__device__ __forceinline__ unsigned short f2bf(float f) {
  union { float f; unsigned int i; } c; c.f = f;
  unsigned int r = c.i + 0x7fffu + ((c.i >> 16) & 1u);
  return (unsigned short)(r >> 16);
}

// ---- dtype detector: flag=1 if buffers are fp32 storage, 0 if bf16 storage ----
__global__ void k_detect(const unsigned short* __restrict__ xq, int nsamp, int* __restrict__ flagp) {
  __shared__ float sm[256];
  int t = threadIdx.x;
  float mx = 0.f;
  for (int i = t; i < nsamp; i += 256) {
    float v = bf2f(xq[i]);
    if (!(v == v)) v = 1e30f;          // NaN -> huge
    mx = fmaxf(mx, fabsf(v));
  }
  sm[t] = mx; __syncthreads();
  for (int o = 128; o > 0; o >>= 1) {
    if (t < o) sm[t] = fmaxf(sm[t], sm[t + o]);
    __syncthreads();
  }
  if (t == 0) *flagp = (sm[0] > 1e6f) ? 1 : 0;
}

// ---- generic convert to fp32 (branch on runtime flag) ----
__global__ void k_cvt(const void* __restrict__ src, float* __restrict__ dst, int n,
                      const int* __restrict__ flagp) {
  int i = blockIdx.x * 256 + threadIdx.x;
  if (i >= n) return;
  if (*flagp) dst[i] = ((const float*)src)[i];
  else        dst[i] = bf2f(((const unsigned short*)src)[i]);
}

__global__ void k_zero_i32(int* p, int n) {
  int i = blockIdx.x * 256 + threadIdx.x;
  if (i < n) p[i] = 0;
}

// ---------------- CSR build ----------------
__global__ void k_deg(const int* __restrict__ dst, int* __restrict__ deg, int E) {
  int e = blockIdx.x * 256 + threadIdx.x;
  if (e < E) atomicAdd(&deg[dst[e]], 1);
}
__global__ void k_scan1(const int* __restrict__ in, int* __restrict__ out, int* __restrict__ bsums, int n) {
  __shared__ int sh[256];
  int t = threadIdx.x, i = blockIdx.x * 256 + t;
  int v = (i < n) ? in[i] : 0;
  sh[t] = v; __syncthreads();
  for (int o = 1; o < 256; o <<= 1) {
    int add = (t >= o) ? sh[t - o] : 0;
    __syncthreads();
    sh[t] += add;
    __syncthreads();
  }
  if (i < n) out[i] = sh[t] - v;   // exclusive within block
  if (t == 255) bsums[blockIdx.x] = sh[255];
}
__global__ void k_scan2(int* bsums, int nb) {
  __shared__ int sh[256];
  int t = threadIdx.x;
  int v = (t < nb) ? bsums[t] : 0;
  sh[t] = v; __syncthreads();
  for (int o = 1; o < 256; o <<= 1) {
    int add = (t >= o) ? sh[t - o] : 0;
    __syncthreads();
    sh[t] += add;
    __syncthreads();
  }
  if (t < nb) bsums[t] = sh[t] - v;  // exclusive
}
__global__ void k_scan3(int* offs, const int* bsums, int n, int etot) {
  int i = blockIdx.x * 256 + threadIdx.x;
  if (i < n) offs[i] += bsums[blockIdx.x];
  if (i == 0) offs[n] = etot;
}
__global__ void k_copy_i32(const int* __restrict__ a, int* __restrict__ b, int n) {
  int i = blockIdx.x * 256 + threadIdx.x;
  if (i < n) b[i] = a[i];
}
__global__ void k_fill(const int* __restrict__ dst, const int* __restrict__ src,
                       int* __restrict__ cursor, int* __restrict__ csr_src, int E) {
  int e = blockIdx.x * 256 + threadIdx.x;
  if (e >= E) return;
  int pos = atomicAdd(&cursor[dst[e]], 1);
  csr_src[pos] = src[e];
}

// ---------- mean aggregation (fp32): one block per node, blockDim = d ----------
__global__ void k_agg(const float* __restrict__ X, const int* __restrict__ offs,
                      const int* __restrict__ ids, float* __restrict__ out, int d) {
  int v = blockIdx.x, c = threadIdx.x;
  int s = offs[v], e = offs[v + 1];
  float acc = 0.f;
  for (int i = s; i < e; ++i) {
    int u = ids[i];
    acc += X[(unsigned long long)u * d + c];
  }
  out[(unsigned long long)v * d + c] = acc / fmaxf((float)(e - s), 1.0f);
}

// ---------- predictor edge features: Ef[p,:] = H[s]*H[d] (fp32), blockDim=256 ----------
__global__ void k_egather(const float* __restrict__ H, const int* __restrict__ ps, const int* __restrict__ pd,
                          const int* __restrict__ ns, const int* __restrict__ nd,
                          int base, int nPos, float* __restrict__ Ef) {
  int p = blockIdx.x, c = threadIdx.x;
  int g = base + p;
  int s, d;
  if (g < nPos) { s = ps[g]; d = pd[g]; }
  else          { s = ns[g - nPos]; d = nd[g - nPos]; }
  Ef[(unsigned long long)p * 256 + c] = H[(unsigned long long)s * 256 + c] * H[(unsigned long long)d * 256 + c];
}

// ---------- fp32 GEMM: C[M,256] (+)= A[M,K] @ B[K,256], optional bias(fp32)/relu ----------
// flags: 1=accumulate into C, 2=add bias, 4=relu.  grid.x = CDIV(M,64)*4, block = 256.
__global__ __launch_bounds__(256) void gemm_f32(
    const float* __restrict__ A, const float* __restrict__ B, float* __restrict__ C,
    const float* __restrict__ bias, int M, int K, int flags) {
  __shared__ float sA[16][68];   // [k][m]  (transposed A tile)
  __shared__ float sB[16][68];   // [k][n]
  int t = threadIdx.x;
  int mBase = (blockIdx.x >> 2) * 64;
  int nBase = (blockIdx.x & 3) * 64;
  int tx = t & 15, ty = t >> 4;

  float acc[4][4];
#pragma unroll
  for (int i = 0; i < 4; ++i)
#pragma unroll
    for (int j = 0; j < 4; ++j) acc[i][j] = 0.f;

  int lr = t >> 2;           // A tile row (m) 0..63
  int lc = (t & 3) * 4;      // A tile col (k) 0,4,8,12
  int br = t >> 4;           // B tile row (k) 0..15
  int bc = (t & 15) * 4;     // B tile col (n)

  for (int k0 = 0; k0 < K; k0 += 16) {
    int arow = mBase + lr; if (arow >= M) arow = M - 1;
    float4 qa = *(const float4*)&A[(unsigned long long)arow * K + k0 + lc];
    float4 qb = *(const float4*)&B[(unsigned long long)(k0 + br) * 256 + nBase + bc];
    __syncthreads();
    sA[lc + 0][lr] = qa.x;
    sA[lc + 1][lr] = qa.y;
    sA[lc + 2][lr] = qa.z;
    sA[lc + 3][lr] = qa.w;
    *(float4*)&sB[br][bc] = qb;
    __syncthreads();
#pragma unroll
    for (int k = 0; k < 16; ++k) {
      float4 av = *(const float4*)&sA[k][ty * 4];
      float4 bv = *(const float4*)&sB[k][tx * 4];
      float a0 = av.x, a1 = av.y, a2 = av.z, a3 = av.w;
      float b0 = bv.x, b1 = bv.y, b2 = bv.z, b3 = bv.w;
      acc[0][0] += a0 * b0; acc[0][1] += a0 * b1; acc[0][2] += a0 * b2; acc[0][3] += a0 * b3;
      acc[1][0] += a1 * b0; acc[1][1] += a1 * b1; acc[1][2] += a1 * b2; acc[1][3] += a1 * b3;
      acc[2][0] += a2 * b0; acc[2][1] += a2 * b1; acc[2][2] += a2 * b2; acc[2][3] += a2 * b3;
      acc[3][0] += a3 * b0; acc[3][1] += a3 * b1; acc[3][2] += a3 * b2; acc[3][3] += a3 * b3;
    }
  }

#pragma unroll
  for (int i = 0; i < 4; ++i) {
    int gr = mBase + ty * 4 + i;
    if (gr >= M) continue;
    unsigned long long idx = (unsigned long long)gr * 256 + nBase + tx * 4;
    float v0 = acc[i][0], v1 = acc[i][1], v2 = acc[i][2], v3 = acc[i][3];
    if (flags & 1) {
      float4 c0 = *(const float4*)&C[idx];
      v0 += c0.x; v1 += c0.y; v2 += c0.z; v3 += c0.w;
    }
    if (flags & 2) {
      int gc = nBase + tx * 4;
      v0 += bias[gc + 0]; v1 += bias[gc + 1];
      v2 += bias[gc + 2]; v3 += bias[gc + 3];
    }
    if (flags & 4) {
      v0 = fmaxf(v0, 0.f); v1 = fmaxf(v1, 0.f); v2 = fmaxf(v2, 0.f); v3 = fmaxf(v3, 0.f);
    }
    float4 r; r.x = v0; r.y = v1; r.z = v2; r.w = v3;
    *(float4*)&C[idx] = r;
  }
}

// ---------- final 256->1 dot: out[p] = Z2[p,:] . wp3 + bp3; dual-dtype store ----------
__global__ void k_finaldot(const float* __restrict__ Z2, const float* __restrict__ wp3,
                           const float* __restrict__ bp3, void* __restrict__ out,
                           int base, int Pc, const int* __restrict__ flagp) {
  int wid = threadIdx.x >> 6, lane = threadIdx.x & 63;
  int p = blockIdx.x * 4 + wid;
  if (p >= Pc) return;
  float4 zv = *(const float4*)&Z2[(unsigned long long)p * 256 + lane * 4];
  float s = zv.x * wp3[lane * 4 + 0] + zv.y * wp3[lane * 4 + 1] +
            zv.z * wp3[lane * 4 + 2] + zv.w * wp3[lane * 4 + 3];
#pragma unroll
  for (int o = 32; o >= 1; o >>= 1) s += __shfl_xor(s, o, 64);
  if (lane == 0) {
    float r = s + bp3[0];
    if (*flagp) ((float*)out)[base + p] = r;
    else        ((unsigned short*)out)[base + p] = f2bf(r);
  }
}

extern "C" void kernel_launch(void* const* d_in, const int* in_sizes, int n_in,
                              void* d_out, int out_size, void* d_ws, size_t ws_size,
                              hipStream_t stream) {
  const int N = 50000, E = 800000, P = 100000, DIN = 128, DH = 256;
  const void* x   = d_in[0];
  const int* esrc = (const int*)d_in[1];
  const int* edst = (const int*)d_in[2];
  const int* psrc = (const int*)d_in[3];
  const int* pdst = (const int*)d_in[4];
  const int* nsrc = (const int*)d_in[5];
  const int* ndst = (const int*)d_in[6];
  const void* Ws0 = d_in[7];  const void* Wn0 = d_in[8];  const void* b0 = d_in[9];
  const void* Ws1 = d_in[10]; const void* Wn1 = d_in[11]; const void* b1 = d_in[12];
  const void* Ws2 = d_in[13]; const void* Wn2 = d_in[14]; const void* b2 = d_in[15];
  const void* Wp1 = d_in[16]; const void* bp1 = d_in[17];
  const void* Wp2 = d_in[18]; const void* bp2 = d_in[19];
  const void* Wp3 = d_in[20]; const void* bp3 = d_in[21];
  (void)in_sizes; (void)n_in; (void)out_size; (void)ws_size;

  // ---- workspace layout (float units) ----
  float* F = (float*)d_ws;
  float* ws0f = F;                       // 32768
  float* wn0f = ws0f + 32768;
  float* ws1f = wn0f + 32768;            // 65536 each
  float* wn1f = ws1f + 65536;
  float* ws2f = wn1f + 65536;
  float* wn2f = ws2f + 65536;
  float* wp1f = wn2f + 65536;
  float* wp2f = wp1f + 65536;
  float* b0f  = wp2f + 65536;            // 256 each
  float* b1f  = b0f + 256;
  float* b2f  = b1f + 256;
  float* bp1f = b2f + 256;
  float* bp2f = bp1f + 256;
  float* wp3f = bp2f + 256;
  float* bp3f = wp3f + 256;              // 4 (use 1)
  float* AG   = bp3f + 4;                // N*256 = 12800000
  float* HA   = AG + 12800000;
  float* HB   = HA + 12800000;
  int* deg   = (int*)(HB + 12800000);
  int* offs  = deg + N;                  // N+1
  int* cur   = offs + (N + 1);
  int* bsums = cur + N;                  // 256
  int* csr   = bsums + 256;              // E
  int* flagp = csr + E;                  // 1

  float* XF  = AG;                               // [N,128]
  float* AGX = AG + (unsigned long long)N * DIN; // [N,128]
  const int PC = 50000;
  float* Z1 = HB;
  float* Z2 = AG;

  // ---- dtype detection (fp32 vs bf16 storage) ----
  k_detect<<<1, 256, 0, stream>>>((const unsigned short*)x, 65536, flagp);

  // ---- convert weights/biases to fp32 ----
  k_cvt<<<CDIV(DIN * DH, 256), 256, 0, stream>>>(Ws0, ws0f, DIN * DH, flagp);
  k_cvt<<<CDIV(DIN * DH, 256), 256, 0, stream>>>(Wn0, wn0f, DIN * DH, flagp);
  k_cvt<<<CDIV(DH * DH, 256), 256, 0, stream>>>(Ws1, ws1f, DH * DH, flagp);
  k_cvt<<<CDIV(DH * DH, 256), 256, 0, stream>>>(Wn1, wn1f, DH * DH, flagp);
  k_cvt<<<CDIV(DH * DH, 256), 256, 0, stream>>>(Ws2, ws2f, DH * DH, flagp);
  k_cvt<<<CDIV(DH * DH, 256), 256, 0, stream>>>(Wn2, wn2f, DH * DH, flagp);
  k_cvt<<<CDIV(DH * DH, 256), 256, 0, stream>>>(Wp1, wp1f, DH * DH, flagp);
  k_cvt<<<CDIV(DH * DH, 256), 256, 0, stream>>>(Wp2, wp2f, DH * DH, flagp);
  k_cvt<<<1, 256, 0, stream>>>(b0,  b0f,  DH, flagp);
  k_cvt<<<1, 256, 0, stream>>>(b1,  b1f,  DH, flagp);
  k_cvt<<<1, 256, 0, stream>>>(b2,  b2f,  DH, flagp);
  k_cvt<<<1, 256, 0, stream>>>(bp1, bp1f, DH, flagp);
  k_cvt<<<1, 256, 0, stream>>>(bp2, bp2f, DH, flagp);
  k_cvt<<<1, 256, 0, stream>>>(Wp3, wp3f, DH, flagp);
  k_cvt<<<1, 256, 0, stream>>>(bp3, bp3f, 1, flagp);

  // ---- CSR build ----
  int nb = CDIV(N, 256);
  k_zero_i32<<<nb, 256, 0, stream>>>(deg, N);
  k_deg<<<CDIV(E, 256), 256, 0, stream>>>(edst, deg, E);
  k_scan1<<<nb, 256, 0, stream>>>(deg, offs, bsums, N);
  k_scan2<<<1, 256, 0, stream>>>(bsums, nb);
  k_scan3<<<nb, 256, 0, stream>>>(offs, bsums, N, E);
  k_copy_i32<<<nb, 256, 0, stream>>>(offs, cur, N);
  k_fill<<<CDIV(E, 256), 256, 0, stream>>>(edst, esrc, cur, csr, E);

  const int G_N = CDIV(N, 64) * 4;
  const int G_P = CDIV(PC, 64) * 4;

  // ---- Layer 0: HA = relu(x@Ws0 + agg(x)@Wn0 + b0) ----
  k_cvt<<<CDIV(N * DIN, 256), 256, 0, stream>>>(x, XF, N * DIN, flagp);
  k_agg<<<N, DIN, 0, stream>>>(XF, offs, csr, AGX, DIN);
  gemm_f32<<<G_N, 256, 0, stream>>>(XF,  ws0f, HA, b0f, N, DIN, 0);
  gemm_f32<<<G_N, 256, 0, stream>>>(AGX, wn0f, HA, b0f, N, DIN, 1 | 2 | 4);

  // ---- Layer 1: HB = relu(HA@Ws1 + agg(HA)@Wn1 + b1) ----
  k_agg<<<N, DH, 0, stream>>>(HA, offs, csr, AG, DH);
  gemm_f32<<<G_N, 256, 0, stream>>>(HA, ws1f, HB, b1f, N, DH, 0);
  gemm_f32<<<G_N, 256, 0, stream>>>(AG, wn1f, HB, b1f, N, DH, 1 | 2 | 4);

  // ---- Layer 2: HA = HB@Ws2 + agg(HB)@Wn2 + b2 (no relu) ----
  k_agg<<<N, DH, 0, stream>>>(HB, offs, csr, AG, DH);
  gemm_f32<<<G_N, 256, 0, stream>>>(HB, ws2f, HA, b2f, N, DH, 0);
  gemm_f32<<<G_N, 256, 0, stream>>>(AG, wn2f, HA, b2f, N, DH, 1 | 2);

  // ---- Predictor: 4 chunks of 50000 pairs (chunks 0,1 = pos; 2,3 = neg) ----
  for (int c = 0; c < 4; ++c) {
    int base = c * PC;
    k_egather<<<PC, DH, 0, stream>>>(HA, psrc, pdst, nsrc, ndst, base, P, AG);  // E-feat
    gemm_f32<<<G_P, 256, 0, stream>>>(AG, wp1f, Z1, bp1f, PC, DH, 2 | 4);       // Z1 = relu(E@Wp1+bp1)
    gemm_f32<<<G_P, 256, 0, stream>>>(Z1, wp2f, Z2, bp2f, PC, DH, 2 | 4);       // Z2 = relu(Z1@Wp2+bp2)
    k_finaldot<<<CDIV(PC, 4), 256, 0, stream>>>(Z2, wp3f, bp3f, d_out, base, PC, flagp);
  }
}

// Round 7
// 1483.256 us; speedup vs baseline: 1.4203x; 1.4203x over previous
//
#include <hip/hip_runtime.h>
#include <hip/hip_bf16.h>

#define CDIV(a, b) (((a) + (b) - 1) / (b))

typedef __attribute__((ext_vector_type(8))) __bf16 bf16x8;
typedef __attribute__((ext_vector_type(4))) float f32x4;

__device__ __forceinline__ float bf2f(unsigned short u) {
  union { unsigned int i; float f; } c; c.i = ((unsigned int)u) << 16; return c.f;
}
__device__ __forceinline__ unsigned short f2bf(float f) {
  union { float f; unsigned int i; } c; c.f = f;
  unsigned int r = c.i + 0x7fffu + ((c.i >> 16) & 1u);
  return (unsigned short)(r >> 16);
}

// ---- dtype detector: flag=1 if buffers are fp32 storage, 0 if bf16 storage ----
__global__ void k_detect(const unsigned short* __restrict__ xq, int nsamp, int* __restrict__ flagp) {
  __shared__ float sm[256];
  int t = threadIdx.x;
  float mx = 0.f;
  for (int i = t; i < nsamp; i += 256) {
    float v = bf2f(xq[i]);
    if (!(v == v)) v = 1e30f;
    mx = fmaxf(mx, fabsf(v));
  }
  sm[t] = mx; __syncthreads();
  for (int o = 128; o > 0; o >>= 1) {
    if (t < o) sm[t] = fmaxf(sm[t], sm[t + o]);
    __syncthreads();
  }
  if (t == 0) *flagp = (sm[0] > 1e6f) ? 1 : 0;
}

// ---- generic convert to fp32 ----
__global__ void k_cvt(const void* __restrict__ src, float* __restrict__ dst, int n,
                      const int* __restrict__ flagp) {
  int i = blockIdx.x * 256 + threadIdx.x;
  if (i >= n) return;
  if (*flagp) dst[i] = ((const float*)src)[i];
  else        dst[i] = bf2f(((const unsigned short*)src)[i]);
}

// ---- weight: W[K,256] -> transposed hi/lo bf16 Bt[256,K] ----
__global__ void k_wsplit(const void* __restrict__ W, unsigned short* __restrict__ Bth,
                         unsigned short* __restrict__ Btl, int K, const int* __restrict__ flagp) {
  int i = blockIdx.x * 256 + threadIdx.x;
  if (i >= K * 256) return;
  int k = i >> 8, n = i & 255;
  float v = (*flagp) ? ((const float*)W)[i] : bf2f(((const unsigned short*)W)[i]);
  unsigned short h = f2bf(v);
  Bth[(size_t)n * K + k] = h;
  Btl[(size_t)n * K + k] = f2bf(v - bf2f(h));
}

// ---- x -> hi/lo split (dual dtype) ----
__global__ void k_split_x(const void* __restrict__ x, unsigned short* __restrict__ oh,
                          unsigned short* __restrict__ ol, int n, const int* __restrict__ flagp) {
  int i = blockIdx.x * 256 + threadIdx.x;
  if (i >= n) return;
  float v = (*flagp) ? ((const float*)x)[i] : bf2f(((const unsigned short*)x)[i]);
  unsigned short h = f2bf(v);
  oh[i] = h;
  ol[i] = f2bf(v - bf2f(h));
}

__global__ void k_zero_i32(int* p, int n) {
  int i = blockIdx.x * 256 + threadIdx.x;
  if (i < n) p[i] = 0;
}

// ---------------- CSR build ----------------
__global__ void k_deg(const int* __restrict__ dst, int* __restrict__ deg, int E) {
  int e = blockIdx.x * 256 + threadIdx.x;
  if (e < E) atomicAdd(&deg[dst[e]], 1);
}
__global__ void k_scan1(const int* __restrict__ in, int* __restrict__ out, int* __restrict__ bsums, int n) {
  __shared__ int sh[256];
  int t = threadIdx.x, i = blockIdx.x * 256 + t;
  int v = (i < n) ? in[i] : 0;
  sh[t] = v; __syncthreads();
  for (int o = 1; o < 256; o <<= 1) {
    int add = (t >= o) ? sh[t - o] : 0;
    __syncthreads();
    sh[t] += add;
    __syncthreads();
  }
  if (i < n) out[i] = sh[t] - v;
  if (t == 255) bsums[blockIdx.x] = sh[255];
}
__global__ void k_scan2(int* bsums, int nb) {
  __shared__ int sh[256];
  int t = threadIdx.x;
  int v = (t < nb) ? bsums[t] : 0;
  sh[t] = v; __syncthreads();
  for (int o = 1; o < 256; o <<= 1) {
    int add = (t >= o) ? sh[t - o] : 0;
    __syncthreads();
    sh[t] += add;
    __syncthreads();
  }
  if (t < nb) bsums[t] = sh[t] - v;
}
__global__ void k_scan3(int* offs, const int* bsums, int n, int etot) {
  int i = blockIdx.x * 256 + threadIdx.x;
  if (i < n) offs[i] += bsums[blockIdx.x];
  if (i == 0) offs[n] = etot;
}
__global__ void k_copy_i32(const int* __restrict__ a, int* __restrict__ b, int n) {
  int i = blockIdx.x * 256 + threadIdx.x;
  if (i < n) b[i] = a[i];
}
__global__ void k_fill(const int* __restrict__ dst, const int* __restrict__ src,
                       int* __restrict__ cursor, int* __restrict__ csr_src, int E) {
  int e = blockIdx.x * 256 + threadIdx.x;
  if (e >= E) return;
  int pos = atomicAdd(&cursor[dst[e]], 1);
  csr_src[pos] = src[e];
}
// per-node insertion sort -> deterministic neighbor order (avg deg 16)
__global__ void k_sortcsr(const int* __restrict__ offs, int* __restrict__ csr, int n) {
  int v = blockIdx.x * 256 + threadIdx.x;
  if (v >= n) return;
  int s = offs[v], e = offs[v + 1];
  for (int i = s + 1; i < e; ++i) {
    int key = csr[i];
    int j = i - 1;
    while (j >= s && csr[j] > key) { csr[j + 1] = csr[j]; --j; }
    csr[j + 1] = key;
  }
}

// ---- layer-0 aggregation from raw x (dual dtype), d=128, writes hi/lo ----
__global__ void k_agg0(const void* __restrict__ x, const int* __restrict__ offs,
                       const int* __restrict__ ids, unsigned short* __restrict__ oh,
                       unsigned short* __restrict__ ol, const int* __restrict__ flagp) {
  int v = blockIdx.x, c = threadIdx.x;
  int fl = *flagp;
  const float* xf = (const float*)x;
  const unsigned short* xu = (const unsigned short*)x;
  int s = offs[v], e = offs[v + 1];
  float acc = 0.f;
  int i = s;
  for (; i + 2 <= e; i += 2) {
    size_t o0 = (size_t)ids[i] * 128 + c;
    size_t o1 = (size_t)ids[i + 1] * 128 + c;
    float a0 = fl ? xf[o0] : bf2f(xu[o0]);
    float a1 = fl ? xf[o1] : bf2f(xu[o1]);
    acc += a0 + a1;
  }
  if (i < e) {
    size_t o0 = (size_t)ids[i] * 128 + c;
    acc += fl ? xf[o0] : bf2f(xu[o0]);
  }
  float a = acc / fmaxf((float)(e - s), 1.0f);
  unsigned short h = f2bf(a);
  oh[(size_t)v * 128 + c] = h;
  ol[(size_t)v * 128 + c] = f2bf(a - bf2f(h));
}

// ---- aggregation from hi/lo pair, d=256, writes hi/lo ----
__global__ void k_aggp(const unsigned short* __restrict__ hi, const unsigned short* __restrict__ lo,
                       const int* __restrict__ offs, const int* __restrict__ ids,
                       unsigned short* __restrict__ oh, unsigned short* __restrict__ ol) {
  int v = blockIdx.x, c = threadIdx.x;
  int s = offs[v], e = offs[v + 1];
  float acc = 0.f;
  int i = s;
  for (; i + 2 <= e; i += 2) {
    size_t o0 = (size_t)ids[i] * 256 + c;
    size_t o1 = (size_t)ids[i + 1] * 256 + c;
    float a0 = bf2f(hi[o0]) + bf2f(lo[o0]);
    float a1 = bf2f(hi[o1]) + bf2f(lo[o1]);
    acc += a0 + a1;
  }
  if (i < e) {
    size_t o0 = (size_t)ids[i] * 256 + c;
    acc += bf2f(hi[o0]) + bf2f(lo[o0]);
  }
  float a = acc / fmaxf((float)(e - s), 1.0f);
  unsigned short h = f2bf(a);
  oh[(size_t)v * 256 + c] = h;
  ol[(size_t)v * 256 + c] = f2bf(a - bf2f(h));
}

// ---- predictor edge features from hi/lo H: E = H[s]*H[d], writes hi/lo ----
__global__ void k_egather2(const unsigned short* __restrict__ Hh, const unsigned short* __restrict__ Hl,
                           const int* __restrict__ ps, const int* __restrict__ pd,
                           const int* __restrict__ ns, const int* __restrict__ nd,
                           int base, int nPos, unsigned short* __restrict__ Eh,
                           unsigned short* __restrict__ El) {
  int p = blockIdx.x, c = threadIdx.x;
  int g = base + p;
  int s, d;
  if (g < nPos) { s = ps[g]; d = pd[g]; }
  else          { s = ns[g - nPos]; d = nd[g - nPos]; }
  size_t so = (size_t)s * 256 + c, dof = (size_t)d * 256 + c;
  float hs = bf2f(Hh[so]) + bf2f(Hl[so]);
  float hd = bf2f(Hh[dof]) + bf2f(Hl[dof]);
  float v = hs * hd;
  unsigned short h = f2bf(v);
  Eh[(size_t)p * 256 + c] = h;
  El[(size_t)p * 256 + c] = f2bf(v - bf2f(h));
}

// ---- fused MFMA GEMM: C[M,256] = A1@B1^T (+ A2@B2^T) + bias, opt relu ----
// All A/B operands are hi/lo bf16 pairs; 3-product split per (i,j).
// NOTE: output buffers must NOT alias any input (ping-pong at call site).
// grid.x = CDIV(M,128)*2, block = 256.
__global__ __launch_bounds__(256) void gemm_fused(
    const unsigned short* __restrict__ A1h, const unsigned short* __restrict__ A1l, int K1,
    const unsigned short* __restrict__ B1h, const unsigned short* __restrict__ B1l,
    const unsigned short* __restrict__ A2h, const unsigned short* __restrict__ A2l, int K2,
    const unsigned short* __restrict__ B2h, const unsigned short* __restrict__ B2l,
    const float* __restrict__ bias, int M, int relu,
    float* __restrict__ Cf, unsigned short* __restrict__ Oh, unsigned short* __restrict__ Ol) {
  __shared__ unsigned short sAh[128 * 40], sAl[128 * 40], sBh[128 * 40], sBl[128 * 40];
  int t = threadIdx.x;
  int m0 = (blockIdx.x >> 1) * 128;
  int n0 = (blockIdx.x & 1) * 128;
  int wid = t >> 6, lane = t & 63;
  int wr = (wid >> 1) * 64, wc = (wid & 1) * 64;
  int quad = lane >> 4, lrow = lane & 15;

  f32x4 acc[4][4];
  const f32x4 z4 = {0.f, 0.f, 0.f, 0.f};
#pragma unroll
  for (int i = 0; i < 4; ++i)
#pragma unroll
    for (int j = 0; j < 4; ++j) acc[i][j] = z4;

  int sr = t >> 2;          // staging row 0..63 (+64 on rep 1)
  int c8 = (t & 3) * 8;     // staging col 0,8,16,24

  for (int pass = 0; pass < 2; ++pass) {
    const unsigned short* Ah = pass ? A2h : A1h;
    if (Ah == 0) continue;
    const unsigned short* Al = pass ? A2l : A1l;
    const unsigned short* Bh = pass ? B2h : B1h;
    const unsigned short* Bl = pass ? B2l : B1l;
    int K = pass ? K2 : K1;

    for (int k0 = 0; k0 < K; k0 += 32) {
#pragma unroll
      for (int rep = 0; rep < 2; ++rep) {
        int r = sr + rep * 64;
        int arow = m0 + r; if (arow >= M) arow = M - 1;
        size_t aoff = (size_t)arow * K + k0 + c8;
        size_t boff = (size_t)(n0 + r) * K + k0 + c8;
        *(uint4*)&sAh[r * 40 + c8] = *(const uint4*)&Ah[aoff];
        *(uint4*)&sAl[r * 40 + c8] = *(const uint4*)&Al[aoff];
        *(uint4*)&sBh[r * 40 + c8] = *(const uint4*)&Bh[boff];
        *(uint4*)&sBl[r * 40 + c8] = *(const uint4*)&Bl[boff];
      }
      __syncthreads();
      bf16x8 ah[4], al[4], bh[4], bl[4];
#pragma unroll
      for (int i = 0; i < 4; ++i) {
        int ar = (wr + i * 16 + lrow) * 40 + quad * 8;
        int br = (wc + i * 16 + lrow) * 40 + quad * 8;
        ah[i] = *(const bf16x8*)&sAh[ar];
        al[i] = *(const bf16x8*)&sAl[ar];
        bh[i] = *(const bf16x8*)&sBh[br];
        bl[i] = *(const bf16x8*)&sBl[br];
      }
#pragma unroll
      for (int i = 0; i < 4; ++i)
#pragma unroll
        for (int j = 0; j < 4; ++j) {
          acc[i][j] = __builtin_amdgcn_mfma_f32_16x16x32_bf16(ah[i], bh[j], acc[i][j], 0, 0, 0);
          acc[i][j] = __builtin_amdgcn_mfma_f32_16x16x32_bf16(al[i], bh[j], acc[i][j], 0, 0, 0);
          acc[i][j] = __builtin_amdgcn_mfma_f32_16x16x32_bf16(ah[i], bl[j], acc[i][j], 0, 0, 0);
        }
      __syncthreads();
    }
  }

  // epilogue: C/D layout col = lane&15, row = (lane>>4)*4 + reg
#pragma unroll
  for (int j = 0; j < 4; ++j) {
    int gc = n0 + wc + j * 16 + lrow;
    float bv = bias[gc];
#pragma unroll
    for (int i = 0; i < 4; ++i) {
#pragma unroll
      for (int rr = 0; rr < 4; ++rr) {
        int gr = m0 + wr + i * 16 + quad * 4 + rr;
        if (gr < M) {
          float v = acc[i][j][rr] + bv;
          if (relu) v = fmaxf(v, 0.f);
          size_t idx = (size_t)gr * 256 + gc;
          if (Cf) Cf[idx] = v;
          if (Oh) {
            unsigned short h = f2bf(v);
            Oh[idx] = h;
            Ol[idx] = f2bf(v - bf2f(h));
          }
        }
      }
    }
  }
}

// ---- final 256->1 dot ----
__global__ void k_finaldot(const float* __restrict__ Z2, const float* __restrict__ wp3,
                           const float* __restrict__ bp3, void* __restrict__ out,
                           int base, int Pc, const int* __restrict__ flagp) {
  int wid = threadIdx.x >> 6, lane = threadIdx.x & 63;
  int p = blockIdx.x * 4 + wid;
  if (p >= Pc) return;
  float4 zv = *(const float4*)&Z2[(size_t)p * 256 + lane * 4];
  float s = zv.x * wp3[lane * 4 + 0] + zv.y * wp3[lane * 4 + 1] +
            zv.z * wp3[lane * 4 + 2] + zv.w * wp3[lane * 4 + 3];
#pragma unroll
  for (int o = 32; o >= 1; o >>= 1) s += __shfl_xor(s, o, 64);
  if (lane == 0) {
    float r = s + bp3[0];
    if (*flagp) ((float*)out)[base + p] = r;
    else        ((unsigned short*)out)[base + p] = f2bf(r);
  }
}

extern "C" void kernel_launch(void* const* d_in, const int* in_sizes, int n_in,
                              void* d_out, int out_size, void* d_ws, size_t ws_size,
                              hipStream_t stream) {
  const int N = 50000, E = 800000, P = 100000, DIN = 128, DH = 256;
  const void* x = d_in[0];
  const int* esrc = (const int*)d_in[1];
  const int* edst = (const int*)d_in[2];
  const int* psrc = (const int*)d_in[3];
  const int* pdst = (const int*)d_in[4];
  const int* nsrc = (const int*)d_in[5];
  const int* ndst = (const int*)d_in[6];
  const void* Ws0 = d_in[7];  const void* Wn0 = d_in[8];  const void* b0 = d_in[9];
  const void* Ws1 = d_in[10]; const void* Wn1 = d_in[11]; const void* b1 = d_in[12];
  const void* Ws2 = d_in[13]; const void* Wn2 = d_in[14]; const void* b2 = d_in[15];
  const void* Wp1 = d_in[16]; const void* bp1 = d_in[17];
  const void* Wp2 = d_in[18]; const void* bp2 = d_in[19];
  const void* Wp3 = d_in[20]; const void* bp3 = d_in[21];
  (void)in_sizes; (void)n_in; (void)out_size; (void)ws_size;

  // ---- workspace layout (u16 units): three ping-pong regions S, G, T ----
  const size_t NH = (size_t)N * DH;          // 12,800,000
  unsigned short* U = (unsigned short*)d_ws;
  unsigned short* Sh = U;                    // region S: [N,256] pair
  unsigned short* Sl = Sh + NH;
  unsigned short* Gh = Sl + NH;              // region G: agg / E ; late: Z2 fp32
  unsigned short* Gl = Gh + NH;
  unsigned short* Th = Gl + NH;              // region T: X pair early; H2 / Z1 later
  unsigned short* Tl = Th + NH;
  unsigned short* Xh = Th;                   // [N,128] pair aliases T
  unsigned short* Xl = Xh + (size_t)N * DIN;
  float* Z2f = (float*)Gh;                   // predictor Z2 fp32 aliases G
  unsigned short* W16 = Tl + NH;             // weight pairs
  unsigned short* ws0h = W16;
  unsigned short* ws0l = ws0h + 32768;
  unsigned short* wn0h = ws0l + 32768;
  unsigned short* wn0l = wn0h + 32768;
  unsigned short* ws1h = wn0l + 32768;
  unsigned short* ws1l = ws1h + 65536;
  unsigned short* wn1h = ws1l + 65536;
  unsigned short* wn1l = wn1h + 65536;
  unsigned short* ws2h = wn1l + 65536;
  unsigned short* ws2l = ws2h + 65536;
  unsigned short* wn2h = ws2l + 65536;
  unsigned short* wn2l = wn2h + 65536;
  unsigned short* wp1h = wn2l + 65536;
  unsigned short* wp1l = wp1h + 65536;
  unsigned short* wp2h = wp1l + 65536;
  unsigned short* wp2l = wp2h + 65536;
  float* FB = (float*)(wp2l + 65536);
  float* b0f  = FB;
  float* b1f  = b0f + 256;
  float* b2f  = b1f + 256;
  float* bp1f = b2f + 256;
  float* bp2f = bp1f + 256;
  float* wp3f = bp2f + 256;
  float* bp3f = wp3f + 256;
  int* deg   = (int*)(bp3f + 4);
  int* offs  = deg + N;
  int* cur   = offs + (N + 1);
  int* bsums = cur + N;
  int* csr   = bsums + 256;
  int* flagp = csr + E;

  // ---- dtype detection ----
  k_detect<<<1, 256, 0, stream>>>((const unsigned short*)x, 65536, flagp);

  // ---- weight split+transpose, bias cvt ----
  k_wsplit<<<CDIV(DIN * DH, 256), 256, 0, stream>>>(Ws0, ws0h, ws0l, DIN, flagp);
  k_wsplit<<<CDIV(DIN * DH, 256), 256, 0, stream>>>(Wn0, wn0h, wn0l, DIN, flagp);
  k_wsplit<<<CDIV(DH * DH, 256), 256, 0, stream>>>(Ws1, ws1h, ws1l, DH, flagp);
  k_wsplit<<<CDIV(DH * DH, 256), 256, 0, stream>>>(Wn1, wn1h, wn1l, DH, flagp);
  k_wsplit<<<CDIV(DH * DH, 256), 256, 0, stream>>>(Ws2, ws2h, ws2l, DH, flagp);
  k_wsplit<<<CDIV(DH * DH, 256), 256, 0, stream>>>(Wn2, wn2h, wn2l, DH, flagp);
  k_wsplit<<<CDIV(DH * DH, 256), 256, 0, stream>>>(Wp1, wp1h, wp1l, DH, flagp);
  k_wsplit<<<CDIV(DH * DH, 256), 256, 0, stream>>>(Wp2, wp2h, wp2l, DH, flagp);
  k_cvt<<<1, 256, 0, stream>>>(b0,  b0f,  DH, flagp);
  k_cvt<<<1, 256, 0, stream>>>(b1,  b1f,  DH, flagp);
  k_cvt<<<1, 256, 0, stream>>>(b2,  b2f,  DH, flagp);
  k_cvt<<<1, 256, 0, stream>>>(bp1, bp1f, DH, flagp);
  k_cvt<<<1, 256, 0, stream>>>(bp2, bp2f, DH, flagp);
  k_cvt<<<1, 256, 0, stream>>>(Wp3, wp3f, DH, flagp);
  k_cvt<<<1, 256, 0, stream>>>(bp3, bp3f, 1, flagp);

  // ---- CSR build (deterministic: sorted adjacency) ----
  int nb = CDIV(N, 256);
  k_zero_i32<<<nb, 256, 0, stream>>>(deg, N);
  k_deg<<<CDIV(E, 256), 256, 0, stream>>>(edst, deg, E);
  k_scan1<<<nb, 256, 0, stream>>>(deg, offs, bsums, N);
  k_scan2<<<1, 256, 0, stream>>>(bsums, nb);
  k_scan3<<<nb, 256, 0, stream>>>(offs, bsums, N, E);
  k_copy_i32<<<nb, 256, 0, stream>>>(offs, cur, N);
  k_fill<<<CDIV(E, 256), 256, 0, stream>>>(edst, esrc, cur, csr, E);
  k_sortcsr<<<nb, 256, 0, stream>>>(offs, csr, N);

  const int G_M = CDIV(N, 128) * 2;   // 782 blocks

  // ---- Layer 0: S = relu(x@Ws0 + agg(x)@Wn0 + b0) ----
  k_split_x<<<CDIV(N * DIN, 256), 256, 0, stream>>>(x, Xh, Xl, N * DIN, flagp);
  k_agg0<<<N, DIN, 0, stream>>>(x, offs, csr, Gh, Gl, flagp);
  gemm_fused<<<G_M, 256, 0, stream>>>(Xh, Xl, DIN, ws0h, ws0l,
                                      Gh, Gl, DIN, wn0h, wn0l,
                                      b0f, N, 1, (float*)0, Sh, Sl);

  // ---- Layer 1: T = relu(S@Ws1 + agg(S)@Wn1 + b1)  (ping-pong S->T) ----
  k_aggp<<<N, DH, 0, stream>>>(Sh, Sl, offs, csr, Gh, Gl);
  gemm_fused<<<G_M, 256, 0, stream>>>(Sh, Sl, DH, ws1h, ws1l,
                                      Gh, Gl, DH, wn1h, wn1l,
                                      b1f, N, 1, (float*)0, Th, Tl);

  // ---- Layer 2: S = T@Ws2 + agg(T)@Wn2 + b2 (no relu)  (T->S) ----
  k_aggp<<<N, DH, 0, stream>>>(Th, Tl, offs, csr, Gh, Gl);
  gemm_fused<<<G_M, 256, 0, stream>>>(Th, Tl, DH, ws2h, ws2l,
                                      Gh, Gl, DH, wn2h, wn2l,
                                      b2f, N, 0, (float*)0, Sh, Sl);

  // ---- Predictor: 4 chunks of 50000 pairs (H = S pair) ----
  const int PC = 50000;
  const int G_P = CDIV(PC, 128) * 2;
  for (int c = 0; c < 4; ++c) {
    int base = c * PC;
    k_egather2<<<PC, DH, 0, stream>>>(Sh, Sl, psrc, pdst, nsrc, ndst, base, P, Gh, Gl);
    // Z1 = relu(E@Wp1 + bp1): G -> T
    gemm_fused<<<G_P, 256, 0, stream>>>(Gh, Gl, DH, wp1h, wp1l,
                                        (unsigned short*)0, (unsigned short*)0, 0,
                                        (unsigned short*)0, (unsigned short*)0,
                                        bp1f, PC, 1, (float*)0, Th, Tl);
    // Z2 = relu(Z1@Wp2 + bp2): T -> Z2f (fp32, aliases G; E is dead)
    gemm_fused<<<G_P, 256, 0, stream>>>(Th, Tl, DH, wp2h, wp2l,
                                        (unsigned short*)0, (unsigned short*)0, 0,
                                        (unsigned short*)0, (unsigned short*)0,
                                        bp2f, PC, 1, Z2f, (unsigned short*)0, (unsigned short*)0);
    k_finaldot<<<CDIV(PC, 4), 256, 0, stream>>>(Z2f, wp3f, bp3f, d_out, base, PC, flagp);
  }
}